// Round 1
// baseline (405.357 us; speedup 1.0000x reference)
//
#include <hip/hip_runtime.h>
#include <cstdint>

#define NNODES 100000
#define NDEG 16
#define DFEAT 128      // node feature dim
#define DEDGE 16       // edge feature dim
#define DAGG  144      // DFEAT + DEDGE
#define KDIM  272      // 2*DFEAT + DEDGE
#define NDOUT 128

// ---------------------------------------------------------------------------
// Kernel 1: per-node aggregation (mean over 16 neighbors of [h[nbr] | ef]).
// One wave (64 lanes) per node.
//   h part : lanes 0..31 own float4 columns (128 f32); half-waves split the
//            16 neighbors 8/8; shfl_xor(32) combines.
//   ef part: lane = (k<<2)|q reads edge_table[eidx[k]] float4 q; xor-tree
//            over k (masks 4,8,16,32) reduces the 16 edges.
// Output: agg[N][144] f32 in workspace ([N][36] float4: 32 h-mean + 4 ef-mean)
// ---------------------------------------------------------------------------
__global__ __launch_bounds__(256) void agg_kernel(
    const float* __restrict__ h, const float* __restrict__ et,
    const int* __restrict__ nidx, const int* __restrict__ eidx,
    float* __restrict__ agg)
{
    int gwave = (blockIdx.x * 256 + threadIdx.x) >> 6;
    int lane  = threadIdx.x & 63;
    if (gwave >= NNODES) return;
    const int n = gwave;

    const float4* __restrict__ h4  = (const float4*)h;
    const float4* __restrict__ et4 = (const float4*)et;
    float4* __restrict__ agg4 = (float4*)agg;

    // ---- h-mean ----
    int col4 = lane & 31;
    float4 acc = make_float4(0.f, 0.f, 0.f, 0.f);
#pragma unroll
    for (int k = (lane >> 5); k < NDEG; k += 2) {
        int nbr = nidx[n * NDEG + k];
        float4 v = h4[(size_t)nbr * (DFEAT / 4) + col4];
        acc.x += v.x; acc.y += v.y; acc.z += v.z; acc.w += v.w;
    }
    acc.x += __shfl_xor(acc.x, 32);
    acc.y += __shfl_xor(acc.y, 32);
    acc.z += __shfl_xor(acc.z, 32);
    acc.w += __shfl_xor(acc.w, 32);

    // ---- edge-feature mean ----
    int ke = lane >> 2, q = lane & 3;
    int e = eidx[n * NDEG + ke];
    float4 ev = et4[(size_t)e * (DEDGE / 4) + q];
#pragma unroll
    for (int m = 4; m < 64; m <<= 1) {
        ev.x += __shfl_xor(ev.x, m);
        ev.y += __shfl_xor(ev.y, m);
        ev.z += __shfl_xor(ev.z, m);
        ev.w += __shfl_xor(ev.w, m);
    }

    const float inv = 1.0f / 16.0f;
    if (lane < 32) {
        float4 o = make_float4(acc.x * inv, acc.y * inv, acc.z * inv, acc.w * inv);
        agg4[(size_t)n * (DAGG / 4) + col4] = o;
    }
    if (lane < 4) {
        float4 o = make_float4(ev.x * inv, ev.y * inv, ev.z * inv, ev.w * inv);
        agg4[(size_t)n * (DAGG / 4) + 32 + lane] = o;
    }
}

// ---------------------------------------------------------------------------
// Kernel 2: out = elu( [h | agg] @ W ), W is [272][128] row-major.
// 256 threads/block, 64-row x 128-col output tile, K staged in 17 chunks of 16.
// Thread (tx = tid&31 -> float4 col, ty = tid>>5 -> rows ty+8i, i=0..7):
// 32 outputs (8 rows x 4 cols) in registers.
// ---------------------------------------------------------------------------
__global__ __launch_bounds__(256) void gemm_elu_kernel(
    const float* __restrict__ h, const float* __restrict__ agg,
    const float* __restrict__ W, float* __restrict__ out)
{
    __shared__ float sF[64][16];    // feat tile   (4 KB)
    __shared__ float sW[16][128];   // W tile      (8 KB)

    const int tid = threadIdx.x;
    const int m0  = blockIdx.x * 64;
    const int tx  = tid & 31;   // float4 column index
    const int ty  = tid >> 5;   // row group 0..7

    float4 acc[8];
#pragma unroll
    for (int i = 0; i < 8; ++i) acc[i] = make_float4(0.f, 0.f, 0.f, 0.f);

    const float4* __restrict__ h4   = (const float4*)h;
    const float4* __restrict__ agg4 = (const float4*)agg;
    const float4* __restrict__ W4   = (const float4*)W;

    // feat-tile load assignment: thread -> (row = tid>>2, quarter = tid&3)
    const int lrow  = tid >> 2;
    const int lq    = tid & 3;
    int grow = m0 + lrow;
    if (grow >= NNODES) grow = NNODES - 1;   // clamp (stores guarded below)

    // W-tile load assignment: 512 float4 per chunk; thread loads f = tid, tid+256
    const int wr0 = tid >> 5;         // rows wr0 and wr0+8
    const int wc  = tid & 31;

    for (int c = 0; c < 17; ++c) {
        // global loads for this chunk
        float4 fv;
        if (c < 8) fv = h4[(size_t)grow * (DFEAT / 4) + c * 4 + lq];
        else       fv = agg4[(size_t)grow * (DAGG / 4) + (c - 8) * 4 + lq];
        float4 wv0 = W4[(size_t)(c * 16 + wr0)     * (NDOUT / 4) + wc];
        float4 wv1 = W4[(size_t)(c * 16 + wr0 + 8) * (NDOUT / 4) + wc];

        __syncthreads();   // previous chunk's compute done before overwrite
        ((float4*)&sF[lrow][0])[lq] = fv;
        ((float4*)&sW[wr0][0])[wc]     = wv0;
        ((float4*)&sW[wr0 + 8][0])[wc] = wv1;
        __syncthreads();

#pragma unroll
        for (int k = 0; k < 16; ++k) {
            float4 w = ((const float4*)&sW[k][0])[tx];
#pragma unroll
            for (int i = 0; i < 8; ++i) {
                float f = sF[ty + 8 * i][k];
                acc[i].x += f * w.x;
                acc[i].y += f * w.y;
                acc[i].z += f * w.z;
                acc[i].w += f * w.w;
            }
        }
    }

    // ---- ELU epilogue + store ----
    float4* __restrict__ out4 = (float4*)out;
#pragma unroll
    for (int i = 0; i < 8; ++i) {
        int r = m0 + ty + 8 * i;
        if (r < NNODES) {
            float4 v = acc[i];
            v.x = v.x > 0.f ? v.x : expm1f(v.x);
            v.y = v.y > 0.f ? v.y : expm1f(v.y);
            v.z = v.z > 0.f ? v.z : expm1f(v.z);
            v.w = v.w > 0.f ? v.w : expm1f(v.w);
            out4[(size_t)r * (NDOUT / 4) + tx] = v;
        }
    }
}

extern "C" void kernel_launch(void* const* d_in, const int* in_sizes, int n_in,
                              void* d_out, int out_size, void* d_ws, size_t ws_size,
                              hipStream_t stream)
{
    const float* h    = (const float*)d_in[0];   // [N,128]
    const float* et   = (const float*)d_in[1];   // [E,16]
    const float* W    = (const float*)d_in[2];   // [272,128]
    const int*   nidx = (const int*)d_in[3];     // [E]
    const int*   eidx = (const int*)d_in[4];     // [E]
    // d_in[5] = segment_ids: unused (fixed degree 16, sorted -> seg = e/16)

    float* agg = (float*)d_ws;                   // [N,144] f32 = 57.6 MB
    float* out = (float*)d_out;                  // [N,128]

    // Phase 1: aggregation — one wave per node
    {
        int waves  = NNODES;
        int blocks = (waves * 64 + 255) / 256;   // 25000
        agg_kernel<<<blocks, 256, 0, stream>>>(h, et, nidx, eidx, agg);
    }
    // Phase 2: fused GEMM + ELU
    {
        int blocks = (NNODES + 63) / 64;         // 1563
        gemm_elu_kernel<<<blocks, 256, 0, stream>>>(h, agg, W, out);
    }
}

// Round 2
// 346.087 us; speedup vs baseline: 1.1713x; 1.1713x over previous
//
#include <hip/hip_runtime.h>
#include <cstdint>

#define NNODES 100000
#define NDEG 16
#define DFEAT 128      // node feature dim
#define DEDGE 16       // edge feature dim
#define DAGG  144      // DFEAT + DEDGE
#define KDIM  272      // 2*DFEAT + DEDGE
#define KPAD  288      // padded to 9*32 for MFMA K-steps
#define NDOUT 128

typedef __attribute__((ext_vector_type(8))) short bf16x8;
typedef __attribute__((ext_vector_type(4))) float f32x4;

__device__ __forceinline__ unsigned short f32_to_bf16_rn(float x) {
    union { float f; unsigned u; } v; v.f = x;
    unsigned r = v.u + 0x7FFF + ((v.u >> 16) & 1);
    return (unsigned short)(r >> 16);
}
__device__ __forceinline__ float bf16_bits_to_f32(unsigned short b) {
    union { unsigned u; float f; } v; v.u = ((unsigned)b) << 16; return v.f;
}

// ---------------------------------------------------------------------------
// Kernel 1 (unchanged): per-node aggregation, one wave per node.
// ---------------------------------------------------------------------------
__global__ __launch_bounds__(256) void agg_kernel(
    const float* __restrict__ h, const float* __restrict__ et,
    const int* __restrict__ nidx, const int* __restrict__ eidx,
    float* __restrict__ agg)
{
    int gwave = (blockIdx.x * 256 + threadIdx.x) >> 6;
    int lane  = threadIdx.x & 63;
    if (gwave >= NNODES) return;
    const int n = gwave;

    const float4* __restrict__ h4  = (const float4*)h;
    const float4* __restrict__ et4 = (const float4*)et;
    float4* __restrict__ agg4 = (float4*)agg;

    int col4 = lane & 31;
    float4 acc = make_float4(0.f, 0.f, 0.f, 0.f);
#pragma unroll
    for (int k = (lane >> 5); k < NDEG; k += 2) {
        int nbr = nidx[n * NDEG + k];
        float4 v = h4[(size_t)nbr * (DFEAT / 4) + col4];
        acc.x += v.x; acc.y += v.y; acc.z += v.z; acc.w += v.w;
    }
    acc.x += __shfl_xor(acc.x, 32);
    acc.y += __shfl_xor(acc.y, 32);
    acc.z += __shfl_xor(acc.z, 32);
    acc.w += __shfl_xor(acc.w, 32);

    int ke = lane >> 2, q = lane & 3;
    int e = eidx[n * NDEG + ke];
    float4 ev = et4[(size_t)e * (DEDGE / 4) + q];
#pragma unroll
    for (int m = 4; m < 64; m <<= 1) {
        ev.x += __shfl_xor(ev.x, m);
        ev.y += __shfl_xor(ev.y, m);
        ev.z += __shfl_xor(ev.z, m);
        ev.w += __shfl_xor(ev.w, m);
    }

    const float inv = 1.0f / 16.0f;
    if (lane < 32) {
        float4 o = make_float4(acc.x * inv, acc.y * inv, acc.z * inv, acc.w * inv);
        agg4[(size_t)n * (DAGG / 4) + col4] = o;
    }
    if (lane < 4) {
        float4 o = make_float4(ev.x * inv, ev.y * inv, ev.z * inv, ev.w * inv);
        agg4[(size_t)n * (DAGG / 4) + 32 + lane] = o;
    }
}

// ---------------------------------------------------------------------------
// Kernel 2: split W [272][128] f32 into transposed bf16 hi/lo: Wt[col][k],
// k padded to 288 with zeros.  Runs once per launch (tiny).
// ---------------------------------------------------------------------------
__global__ __launch_bounds__(256) void wt_split_kernel(
    const float* __restrict__ W,
    unsigned short* __restrict__ Wt_hi, unsigned short* __restrict__ Wt_lo)
{
    int i = blockIdx.x * 256 + threadIdx.x;          // i over 128*288
    if (i >= NDOUT * KPAD) return;
    int n = i / KPAD;
    int k = i - n * KPAD;
    float val = (k < KDIM) ? W[(size_t)k * NDOUT + n] : 0.0f;
    unsigned short hi = f32_to_bf16_rn(val);
    float hif = bf16_bits_to_f32(hi);
    unsigned short lo = f32_to_bf16_rn(val - hif);
    Wt_hi[i] = hi;
    Wt_lo[i] = lo;
}

// ---------------------------------------------------------------------------
// Kernel 3: out = elu( [h | agg] @ W ) via split-bf16 MFMA (3 products).
// 256 threads = 4 waves; tile 64 rows x 128 cols; K = 288 in 9 steps of 32.
// Wave w computes rows [w*16, w*16+16) x all 128 cols:
//   8 col-tiles x 9 k-steps x 3 mfma_f32_16x16x32_bf16.
// LDS rows padded to 40 bf16 (80B: 16B-aligned, 2-way bank alias = free).
// ---------------------------------------------------------------------------
__global__ __launch_bounds__(256) void gemm_mfma_kernel(
    const float* __restrict__ h, const float* __restrict__ agg,
    const unsigned short* __restrict__ Wt_hi,
    const unsigned short* __restrict__ Wt_lo,
    float* __restrict__ out)
{
    __shared__ unsigned short sA_hi[64][40];
    __shared__ unsigned short sA_lo[64][40];
    __shared__ unsigned short sB_hi[128][40];
    __shared__ unsigned short sB_lo[128][40];

    const int tid  = threadIdx.x;
    const int wave = tid >> 6;
    const int lane = tid & 63;
    const int m0   = blockIdx.x * 64;

    const float4* __restrict__ h4   = (const float4*)h;
    const float4* __restrict__ agg4 = (const float4*)agg;

    // A staging: idx = tid and tid+256 -> row = idx>>3 (0..63), q = idx&7
    const int r0 = tid >> 3;           // rows r0 and r0+32
    const int q0 = tid & 7;            // k-quarter: k = k0 + q0*4
    int grow0 = m0 + r0;       if (grow0 >= NNODES) grow0 = NNODES - 1;
    int grow1 = m0 + r0 + 32;  if (grow1 >= NNODES) grow1 = NNODES - 1;

    // B staging: idx = tid and tid+256 -> col = idx>>2 (0..127), seg = idx&3
    const int bc0 = tid >> 2;          // cols bc0 and bc0+64
    const int bs0 = tid & 3;           // 16B segment: k-offset bs0*8

    f32x4 acc[8];
#pragma unroll
    for (int n = 0; n < 8; ++n) acc[n] = (f32x4){0.f, 0.f, 0.f, 0.f};

    const int rA = (wave << 4) + (lane & 15);
    const int ko = (lane >> 4) << 3;

    for (int c = 0; c < 9; ++c) {
        const int k0 = c * 32;

        // ---- global loads (regs) ----
        float4 a0, a1;
        {
            int k = k0 + q0 * 4;
            if (k < DFEAT) {
                a0 = h4[(size_t)grow0 * (DFEAT / 4) + (k >> 2)];
                a1 = h4[(size_t)grow1 * (DFEAT / 4) + (k >> 2)];
            } else if (k < KDIM) {
                a0 = agg4[(size_t)grow0 * (DAGG / 4) + ((k - DFEAT) >> 2)];
                a1 = agg4[(size_t)grow1 * (DAGG / 4) + ((k - DFEAT) >> 2)];
            } else {
                a0 = make_float4(0.f, 0.f, 0.f, 0.f);
                a1 = a0;
            }
        }
        uint4 bh0 = *(const uint4*)(Wt_hi + (size_t)bc0 * KPAD + k0 + bs0 * 8);
        uint4 bh1 = *(const uint4*)(Wt_hi + (size_t)(bc0 + 64) * KPAD + k0 + bs0 * 8);
        uint4 bl0 = *(const uint4*)(Wt_lo + (size_t)bc0 * KPAD + k0 + bs0 * 8);
        uint4 bl1 = *(const uint4*)(Wt_lo + (size_t)(bc0 + 64) * KPAD + k0 + bs0 * 8);

        __syncthreads();   // previous step's LDS reads complete

        // ---- A: split f32 -> bf16 hi/lo, write LDS ----
        {
            ushort4 ah, al;
            ah.x = f32_to_bf16_rn(a0.x); al.x = f32_to_bf16_rn(a0.x - bf16_bits_to_f32(ah.x));
            ah.y = f32_to_bf16_rn(a0.y); al.y = f32_to_bf16_rn(a0.y - bf16_bits_to_f32(ah.y));
            ah.z = f32_to_bf16_rn(a0.z); al.z = f32_to_bf16_rn(a0.z - bf16_bits_to_f32(ah.z));
            ah.w = f32_to_bf16_rn(a0.w); al.w = f32_to_bf16_rn(a0.w - bf16_bits_to_f32(ah.w));
            *(ushort4*)&sA_hi[r0][q0 * 4] = ah;
            *(ushort4*)&sA_lo[r0][q0 * 4] = al;
            ah.x = f32_to_bf16_rn(a1.x); al.x = f32_to_bf16_rn(a1.x - bf16_bits_to_f32(ah.x));
            ah.y = f32_to_bf16_rn(a1.y); al.y = f32_to_bf16_rn(a1.y - bf16_bits_to_f32(ah.y));
            ah.z = f32_to_bf16_rn(a1.z); al.z = f32_to_bf16_rn(a1.z - bf16_bits_to_f32(ah.z));
            ah.w = f32_to_bf16_rn(a1.w); al.w = f32_to_bf16_rn(a1.w - bf16_bits_to_f32(ah.w));
            *(ushort4*)&sA_hi[r0 + 32][q0 * 4] = ah;
            *(ushort4*)&sA_lo[r0 + 32][q0 * 4] = al;
        }
        // ---- B: already bf16, write LDS ----
        *(uint4*)&sB_hi[bc0][bs0 * 8]      = bh0;
        *(uint4*)&sB_hi[bc0 + 64][bs0 * 8] = bh1;
        *(uint4*)&sB_lo[bc0][bs0 * 8]      = bl0;
        *(uint4*)&sB_lo[bc0 + 64][bs0 * 8] = bl1;

        __syncthreads();

        // ---- MFMA ----
        bf16x8 ahi = *(const bf16x8*)&sA_hi[rA][ko];
        bf16x8 alo = *(const bf16x8*)&sA_lo[rA][ko];
#pragma unroll
        for (int n = 0; n < 8; ++n) {
            bf16x8 bhi = *(const bf16x8*)&sB_hi[n * 16 + (lane & 15)][ko];
            bf16x8 blo = *(const bf16x8*)&sB_lo[n * 16 + (lane & 15)][ko];
            acc[n] = __builtin_amdgcn_mfma_f32_16x16x32_bf16(ahi, bhi, acc[n], 0, 0, 0);
            acc[n] = __builtin_amdgcn_mfma_f32_16x16x32_bf16(alo, bhi, acc[n], 0, 0, 0);
            acc[n] = __builtin_amdgcn_mfma_f32_16x16x32_bf16(ahi, blo, acc[n], 0, 0, 0);
        }
    }

    // ---- ELU epilogue + store (C/D: col=lane&15, row=(lane>>4)*4+reg) ----
    const int crow = m0 + (wave << 4) + ((lane >> 4) << 2);
    const int ccol = lane & 15;
#pragma unroll
    for (int n = 0; n < 8; ++n) {
#pragma unroll
        for (int r = 0; r < 4; ++r) {
            int rr = crow + r;
            if (rr < NNODES) {
                float v = acc[n][r];
                v = v > 0.f ? v : expm1f(v);
                out[(size_t)rr * NDOUT + n * 16 + ccol] = v;
            }
        }
    }
}

extern "C" void kernel_launch(void* const* d_in, const int* in_sizes, int n_in,
                              void* d_out, int out_size, void* d_ws, size_t ws_size,
                              hipStream_t stream)
{
    const float* h    = (const float*)d_in[0];   // [N,128]
    const float* et   = (const float*)d_in[1];   // [E,16]
    const float* W    = (const float*)d_in[2];   // [272,128]
    const int*   nidx = (const int*)d_in[3];     // [E]
    const int*   eidx = (const int*)d_in[4];     // [E]
    // d_in[5] = segment_ids: unused (fixed degree 16, sorted -> seg = e/16)

    float* agg = (float*)d_ws;                               // [N,144] f32 = 57.6 MB
    unsigned short* Wt_hi = (unsigned short*)(agg + (size_t)NNODES * DAGG);
    unsigned short* Wt_lo = Wt_hi + (size_t)NDOUT * KPAD;    // 2 x 73.7 KB
    float* out = (float*)d_out;                              // [N,128]

    // Phase 0: split+transpose W (tiny)
    wt_split_kernel<<<(NDOUT * KPAD + 255) / 256, 256, 0, stream>>>(W, Wt_hi, Wt_lo);
    // Phase 1: aggregation — one wave per node
    agg_kernel<<<(NNODES * 64 + 255) / 256, 256, 0, stream>>>(h, et, nidx, eidx, agg);
    // Phase 2: GEMM + ELU via split-bf16 MFMA
    gemm_mfma_kernel<<<(NNODES + 63) / 64, 256, 0, stream>>>(h, agg, Wt_hi, Wt_lo, out);
}

// Round 3
// 345.079 us; speedup vs baseline: 1.1747x; 1.0029x over previous
//
#include <hip/hip_runtime.h>
#include <cstdint>

#define NNODES 100000
#define NDEG 16
#define DFEAT 128      // node feature dim
#define DEDGE 16       // edge feature dim
#define KDIM  272      // 2*DFEAT + DEDGE
#define KPAD  288      // padded to 9*32 for MFMA K-steps
#define NDOUT 128
#define NKSTEP 9       // KPAD/32

typedef __attribute__((ext_vector_type(8))) short bf16x8;
typedef __attribute__((ext_vector_type(4))) short s16x4;
typedef __attribute__((ext_vector_type(4))) float f32x4;

__device__ __forceinline__ unsigned short f32_to_bf16_rn(float x) {
    union { float f; unsigned u; } v; v.f = x;
    unsigned r = v.u + 0x7FFF + ((v.u >> 16) & 1);
    return (unsigned short)(r >> 16);
}
__device__ __forceinline__ float bf16_bits_to_f32(unsigned short b) {
    union { unsigned u; float f; } v; v.u = ((unsigned)b) << 16; return v.f;
}

// ---------------------------------------------------------------------------
// Prep A: A[n][k] bf16, k<128 = hi(h[n][k]).  (k>=128 written by agg_kernel.)
// thread -> (n = t>>4, c8 = t&15): 8 cols, read 32B f32, write 16B bf16.
// ---------------------------------------------------------------------------
__global__ __launch_bounds__(256) void prep_h_kernel(
    const float* __restrict__ h, short* __restrict__ A)
{
    int t = blockIdx.x * 256 + threadIdx.x;
    if (t >= NNODES * 16) return;
    int n  = t >> 4;
    int c8 = t & 15;
    const float4* __restrict__ h4 = (const float4*)h;
    float4 v0 = h4[(size_t)n * 32 + c8 * 2];
    float4 v1 = h4[(size_t)n * 32 + c8 * 2 + 1];
    bf16x8 o;
    o[0] = (short)f32_to_bf16_rn(v0.x); o[1] = (short)f32_to_bf16_rn(v0.y);
    o[2] = (short)f32_to_bf16_rn(v0.z); o[3] = (short)f32_to_bf16_rn(v0.w);
    o[4] = (short)f32_to_bf16_rn(v1.x); o[5] = (short)f32_to_bf16_rn(v1.y);
    o[6] = (short)f32_to_bf16_rn(v1.z); o[7] = (short)f32_to_bf16_rn(v1.w);
    *(bf16x8*)(A + (size_t)n * KPAD + c8 * 8) = o;
}

// ---------------------------------------------------------------------------
// Prep W: pack W [272][128] f32 into MFMA-fragment-ordered bf16 hi/lo:
// Bpack[(c*8+n)*64 + lane][j] = split(W[k][col]),
//   col = n*16 + (lane&15), k = c*32 + (lane>>4)*8 + j  (zero-padded k>=272).
// One thread per (c,n,lane).
// ---------------------------------------------------------------------------
__global__ __launch_bounds__(256) void wt_pack_kernel(
    const float* __restrict__ W, short* __restrict__ Bh, short* __restrict__ Bl)
{
    int t = blockIdx.x * 256 + threadIdx.x;
    if (t >= NKSTEP * 8 * 64) return;
    int c   = t >> 9;
    int rem = t & 511;
    int n   = rem >> 6;
    int l   = rem & 63;
    int col = n * 16 + (l & 15);
    int kb  = l >> 4;
    bf16x8 hv, lv;
#pragma unroll
    for (int j = 0; j < 8; ++j) {
        int k = c * 32 + kb * 8 + j;
        float val = (k < KDIM) ? W[(size_t)k * NDOUT + col] : 0.0f;
        unsigned short hi = f32_to_bf16_rn(val);
        unsigned short lo = f32_to_bf16_rn(val - bf16_bits_to_f32(hi));
        hv[j] = (short)hi; lv[j] = (short)lo;
    }
    *(bf16x8*)(Bh + (size_t)t * 8) = hv;
    *(bf16x8*)(Bl + (size_t)t * 8) = lv;
}

// ---------------------------------------------------------------------------
// Aggregation: one wave per node. Gathers neighbor rows from A (bf16 hi,
// 256 B/row instead of 512 B f32), accumulates in f32, writes mean as bf16
// into A[n][128..287] (ef-mean at 256..271, zero tail 272..287).
//   lane = g*16 + c8 : c8 -> cols c8*8..+7, g -> neighbors {g, g+4, g+8, g+12}
// ---------------------------------------------------------------------------
__global__ __launch_bounds__(256) void agg_kernel(
    short* __restrict__ A, const float* __restrict__ et,
    const int* __restrict__ nidx, const int* __restrict__ eidx)
{
    int gwave = (blockIdx.x * 256 + threadIdx.x) >> 6;
    int lane  = threadIdx.x & 63;
    if (gwave >= NNODES) return;
    const int n = gwave;
    const int c8 = lane & 15;
    const int g  = lane >> 4;
    const float inv = 1.0f / 16.0f;

    // ---- h-mean (gather bf16 rows of A) ----
    float acc[8];
#pragma unroll
    for (int j = 0; j < 8; ++j) acc[j] = 0.f;
#pragma unroll
    for (int t = 0; t < 4; ++t) {
        int nbr = nidx[n * NDEG + t * 4 + g];
        bf16x8 v = *(const bf16x8*)(A + (size_t)nbr * KPAD + c8 * 8);
#pragma unroll
        for (int j = 0; j < 8; ++j) acc[j] += bf16_bits_to_f32((unsigned short)v[j]);
    }
#pragma unroll
    for (int j = 0; j < 8; ++j) {
        acc[j] += __shfl_xor(acc[j], 16);
        acc[j] += __shfl_xor(acc[j], 32);
    }
    if (g == 0) {
        bf16x8 o;
#pragma unroll
        for (int j = 0; j < 8; ++j) o[j] = (short)f32_to_bf16_rn(acc[j] * inv);
        *(bf16x8*)(A + (size_t)n * KPAD + DFEAT + c8 * 8) = o;
    }

    // ---- edge-feature mean (f32 gather from edge_table) ----
    const float4* __restrict__ et4 = (const float4*)et;
    int ke = lane >> 2, q = lane & 3;
    int e = eidx[n * NDEG + ke];
    float4 ev = et4[(size_t)e * (DEDGE / 4) + q];
#pragma unroll
    for (int m = 4; m < 64; m <<= 1) {
        ev.x += __shfl_xor(ev.x, m);
        ev.y += __shfl_xor(ev.y, m);
        ev.z += __shfl_xor(ev.z, m);
        ev.w += __shfl_xor(ev.w, m);
    }
    if (lane < 4) {
        s16x4 o;
        o[0] = (short)f32_to_bf16_rn(ev.x * inv);
        o[1] = (short)f32_to_bf16_rn(ev.y * inv);
        o[2] = (short)f32_to_bf16_rn(ev.z * inv);
        o[3] = (short)f32_to_bf16_rn(ev.w * inv);
        *(s16x4*)(A + (size_t)n * KPAD + 256 + lane * 4) = o;
    }
    // ---- zero tail k = 272..287 ----
    if (lane == 4) *(bf16x8*)(A + (size_t)n * KPAD + 272) = (bf16x8)0;
    if (lane == 5) *(bf16x8*)(A + (size_t)n * KPAD + 280) = (bf16x8)0;
}

// ---------------------------------------------------------------------------
// GEMM + ELU: out = elu(A_bf16 @ (W_hi + W_lo)).  LDS-free, barrier-free.
// 4 waves/block; wave owns 32 rows x 128 cols (2 row-frags x 8 col-tiles).
// Per k-step: 2 A-frag loads (16B/lane, L1/L2-hit) + 16 coalesced B-frag
// loads (Bpack fragment-ordered, L2-resident) + 32 mfma_f32_16x16x32_bf16.
// ---------------------------------------------------------------------------
__global__ __launch_bounds__(256) void gemm_kernel(
    const short* __restrict__ A, const short* __restrict__ Bh,
    const short* __restrict__ Bl, float* __restrict__ out)
{
    const int tid  = threadIdx.x;
    const int wave = tid >> 6;
    const int lane = tid & 63;
    const int m0   = blockIdx.x * 128 + wave * 32;
    const int m    = lane & 15;
    const int kb   = lane >> 4;

    int r0 = m0 + m;      if (r0 >= NNODES) r0 = NNODES - 1;
    int r1 = m0 + 16 + m; if (r1 >= NNODES) r1 = NNODES - 1;

    const short* pa0 = A + (size_t)r0 * KPAD + kb * 8;
    const short* pa1 = A + (size_t)r1 * KPAD + kb * 8;

    f32x4 acc0[8], acc1[8];
#pragma unroll
    for (int n = 0; n < 8; ++n) {
        acc0[n] = (f32x4){0.f, 0.f, 0.f, 0.f};
        acc1[n] = (f32x4){0.f, 0.f, 0.f, 0.f};
    }

#pragma unroll
    for (int c = 0; c < NKSTEP; ++c) {
        bf16x8 a0 = *(const bf16x8*)(pa0 + c * 32);
        bf16x8 a1 = *(const bf16x8*)(pa1 + c * 32);
        const short* pb = (const short*)((size_t)(c * 8) * 64 * 8 + (size_t)lane * 8);
#pragma unroll
        for (int n = 0; n < 8; ++n) {
            size_t off = ((size_t)(c * 8 + n) * 64 + lane) * 8;
            bf16x8 bh = *(const bf16x8*)(Bh + off);
            bf16x8 bl = *(const bf16x8*)(Bl + off);
            acc0[n] = __builtin_amdgcn_mfma_f32_16x16x32_bf16(a0, bh, acc0[n], 0, 0, 0);
            acc0[n] = __builtin_amdgcn_mfma_f32_16x16x32_bf16(a0, bl, acc0[n], 0, 0, 0);
            acc1[n] = __builtin_amdgcn_mfma_f32_16x16x32_bf16(a1, bh, acc1[n], 0, 0, 0);
            acc1[n] = __builtin_amdgcn_mfma_f32_16x16x32_bf16(a1, bl, acc1[n], 0, 0, 0);
        }
        (void)pb;
    }

    // ---- ELU epilogue + store (C/D: col = lane&15, row = (lane>>4)*4 + reg) ----
    const int colb   = lane & 15;
    const int rbase0 = m0 + ((lane >> 4) << 2);
#pragma unroll
    for (int n = 0; n < 8; ++n) {
#pragma unroll
        for (int r = 0; r < 4; ++r) {
            int row = rbase0 + r;
            if (row < NNODES) {
                float v = acc0[n][r];
                v = v > 0.f ? v : expm1f(v);
                out[(size_t)row * NDOUT + n * 16 + colb] = v;
            }
            int row1 = rbase0 + 16 + r;
            if (row1 < NNODES) {
                float v = acc1[n][r];
                v = v > 0.f ? v : expm1f(v);
                out[(size_t)row1 * NDOUT + n * 16 + colb] = v;
            }
        }
    }
}

extern "C" void kernel_launch(void* const* d_in, const int* in_sizes, int n_in,
                              void* d_out, int out_size, void* d_ws, size_t ws_size,
                              hipStream_t stream)
{
    const float* h    = (const float*)d_in[0];   // [N,128]
    const float* et   = (const float*)d_in[1];   // [E,16]
    const float* W    = (const float*)d_in[2];   // [272,128]
    const int*   nidx = (const int*)d_in[3];     // [E]
    const int*   eidx = (const int*)d_in[4];     // [E]
    // d_in[5] = segment_ids: unused (fixed degree 16, sorted -> seg = e/16)

    short* A  = (short*)d_ws;                    // [N][288] bf16 = 57.6 MB
    short* Bh = A + (size_t)NNODES * KPAD;       // fragment-packed W hi (73.7 KB)
    short* Bl = Bh + (size_t)NKSTEP * 8 * 64 * 8;
    float* out = (float*)d_out;                  // [N,128]

    // Prep (independent; both before dependents)
    wt_pack_kernel<<<(NKSTEP * 8 * 64 + 255) / 256, 256, 0, stream>>>(W, Bh, Bl);
    prep_h_kernel<<<(NNODES * 16 + 255) / 256, 256, 0, stream>>>(h, A);
    // Aggregation: one wave per node, bf16 gathers
    agg_kernel<<<(NNODES * 64 + 255) / 256, 256, 0, stream>>>(A, et, nidx, eidx);
    // GEMM + ELU, LDS-free
    gemm_kernel<<<(NNODES + 127) / 128, 256, 0, stream>>>(A, Bh, Bl, out);
}

// Round 4
// 313.972 us; speedup vs baseline: 1.2911x; 1.0991x over previous
//
#include <hip/hip_runtime.h>
#include <cstdint>

#define NNODES 100000
#define NDEG 16
#define DFEAT 128      // node feature dim
#define DEDGE 16       // edge feature dim
#define KDIM  272      // 2*DFEAT + DEDGE
#define KPAD  288      // padded to 9*32 for MFMA K-steps
#define NDOUT 128
#define NKSTEP 9       // KPAD/32

typedef __attribute__((ext_vector_type(8))) short bf16x8;
typedef __attribute__((ext_vector_type(4))) short s16x4;
typedef __attribute__((ext_vector_type(4))) float f32x4;

__device__ __forceinline__ unsigned short f32_to_bf16_rn(float x) {
    union { float f; unsigned u; } v; v.f = x;
    unsigned r = v.u + 0x7FFF + ((v.u >> 16) & 1);
    return (unsigned short)(r >> 16);
}
__device__ __forceinline__ float bf16_bits_to_f32(unsigned short b) {
    union { unsigned u; float f; } v; v.u = ((unsigned)b) << 16; return v.f;
}

// ---------------------------------------------------------------------------
// Prep A: A[n][k] bf16, k<128 = hi(h[n][k]).  (k>=128 written by agg_kernel.)
// ---------------------------------------------------------------------------
__global__ __launch_bounds__(256) void prep_h_kernel(
    const float* __restrict__ h, short* __restrict__ A)
{
    int t = blockIdx.x * 256 + threadIdx.x;
    if (t >= NNODES * 16) return;
    int n  = t >> 4;
    int c8 = t & 15;
    const float4* __restrict__ h4 = (const float4*)h;
    float4 v0 = h4[(size_t)n * 32 + c8 * 2];
    float4 v1 = h4[(size_t)n * 32 + c8 * 2 + 1];
    bf16x8 o;
    o[0] = (short)f32_to_bf16_rn(v0.x); o[1] = (short)f32_to_bf16_rn(v0.y);
    o[2] = (short)f32_to_bf16_rn(v0.z); o[3] = (short)f32_to_bf16_rn(v0.w);
    o[4] = (short)f32_to_bf16_rn(v1.x); o[5] = (short)f32_to_bf16_rn(v1.y);
    o[6] = (short)f32_to_bf16_rn(v1.z); o[7] = (short)f32_to_bf16_rn(v1.w);
    *(bf16x8*)(A + (size_t)n * KPAD + c8 * 8) = o;
}

// ---------------------------------------------------------------------------
// Prep W: pack W [272][128] f32 into MFMA-fragment-ordered bf16 hi/lo:
// Bpack[(c*8+n)*64 + lane][j] = split(W[k][col]),
//   col = n*16 + (lane&15), k = c*32 + (lane>>4)*8 + j  (zero-padded k>=272).
// ---------------------------------------------------------------------------
__global__ __launch_bounds__(256) void wt_pack_kernel(
    const float* __restrict__ W, short* __restrict__ Bh, short* __restrict__ Bl)
{
    int t = blockIdx.x * 256 + threadIdx.x;
    if (t >= NKSTEP * 8 * 64) return;
    int c   = t >> 9;
    int rem = t & 511;
    int n   = rem >> 6;
    int l   = rem & 63;
    int col = n * 16 + (l & 15);
    int kb  = l >> 4;
    bf16x8 hv, lv;
#pragma unroll
    for (int j = 0; j < 8; ++j) {
        int k = c * 32 + kb * 8 + j;
        float val = (k < KDIM) ? W[(size_t)k * NDOUT + col] : 0.0f;
        unsigned short hi = f32_to_bf16_rn(val);
        unsigned short lo = f32_to_bf16_rn(val - bf16_bits_to_f32(hi));
        hv[j] = (short)hi; lv[j] = (short)lo;
    }
    *(bf16x8*)(Bh + (size_t)t * 8) = hv;
    *(bf16x8*)(Bl + (size_t)t * 8) = lv;
}

// ---------------------------------------------------------------------------
// Aggregation (unchanged): one wave per node, bf16 gathers from A, means
// written as bf16 into A[n][128..287].
// ---------------------------------------------------------------------------
__global__ __launch_bounds__(256) void agg_kernel(
    short* __restrict__ A, const float* __restrict__ et,
    const int* __restrict__ nidx, const int* __restrict__ eidx)
{
    int gwave = (blockIdx.x * 256 + threadIdx.x) >> 6;
    int lane  = threadIdx.x & 63;
    if (gwave >= NNODES) return;
    const int n = gwave;
    const int c8 = lane & 15;
    const int g  = lane >> 4;
    const float inv = 1.0f / 16.0f;

    float acc[8];
#pragma unroll
    for (int j = 0; j < 8; ++j) acc[j] = 0.f;
#pragma unroll
    for (int t = 0; t < 4; ++t) {
        int nbr = nidx[n * NDEG + t * 4 + g];
        bf16x8 v = *(const bf16x8*)(A + (size_t)nbr * KPAD + c8 * 8);
#pragma unroll
        for (int j = 0; j < 8; ++j) acc[j] += bf16_bits_to_f32((unsigned short)v[j]);
    }
#pragma unroll
    for (int j = 0; j < 8; ++j) {
        acc[j] += __shfl_xor(acc[j], 16);
        acc[j] += __shfl_xor(acc[j], 32);
    }
    if (g == 0) {
        bf16x8 o;
#pragma unroll
        for (int j = 0; j < 8; ++j) o[j] = (short)f32_to_bf16_rn(acc[j] * inv);
        *(bf16x8*)(A + (size_t)n * KPAD + DFEAT + c8 * 8) = o;
    }

    const float4* __restrict__ et4 = (const float4*)et;
    int ke = lane >> 2, q = lane & 3;
    int e = eidx[n * NDEG + ke];
    float4 ev = et4[(size_t)e * (DEDGE / 4) + q];
#pragma unroll
    for (int m = 4; m < 64; m <<= 1) {
        ev.x += __shfl_xor(ev.x, m);
        ev.y += __shfl_xor(ev.y, m);
        ev.z += __shfl_xor(ev.z, m);
        ev.w += __shfl_xor(ev.w, m);
    }
    if (lane < 4) {
        s16x4 o;
        o[0] = (short)f32_to_bf16_rn(ev.x * inv);
        o[1] = (short)f32_to_bf16_rn(ev.y * inv);
        o[2] = (short)f32_to_bf16_rn(ev.z * inv);
        o[3] = (short)f32_to_bf16_rn(ev.w * inv);
        *(s16x4*)(A + (size_t)n * KPAD + 256 + lane * 4) = o;
    }
    if (lane == 4) *(bf16x8*)(A + (size_t)n * KPAD + 272) = (bf16x8)0;
    if (lane == 5) *(bf16x8*)(A + (size_t)n * KPAD + 280) = (bf16x8)0;
}

// ---------------------------------------------------------------------------
// GEMM + ELU: out = elu(A_bf16 @ (W_hi + W_lo)).
// Block = 64 rows x 128 cols, 4 waves.  Wave w owns cols [w*32, w*32+32):
// B-frags (hi+lo, all 9 k-chunks) REGISTER-RESIDENT (144 VGPR), loaded once.
// A staged into LDS in fragment order -> all compute ds_read_b128 are
// lane-linear (conflict-free).  One barrier per block.
//   LDS unit (f*9+c)*64 + lane  <- A[m0+f*16+(lane&15)][c*32+(lane>>4)*8 ..+8]
// ---------------------------------------------------------------------------
__global__ __launch_bounds__(256, 2) void gemm_kernel(
    const short* __restrict__ A, const short* __restrict__ Bh,
    const short* __restrict__ Bl, float* __restrict__ out)
{
    __shared__ short sA[4 * NKSTEP * 64 * 8];   // 36 KB, fragment-ordered

    const int tid  = threadIdx.x;
    const int w    = tid >> 6;
    const int lane = tid & 63;
    const int m0   = blockIdx.x * 64;

    // ---- B preload: n-tiles {2w, 2w+1}, all k-chunks (coalesced, L2-hot) ----
    bf16x8 bh[2][NKSTEP], bl[2][NKSTEP];
#pragma unroll
    for (int n = 0; n < 2; ++n)
#pragma unroll
        for (int c = 0; c < NKSTEP; ++c) {
            size_t off = ((size_t)(c * 8 + (w * 2 + n)) * 64 + lane) * 8;
            bh[n][c] = *(const bf16x8*)(Bh + off);
            bl[n][c] = *(const bf16x8*)(Bl + off);
        }

    // ---- A staging: thread = f*64 + g*16 + i stages (row m0+f*16+i, chunk p, kb g) ----
    {
        const int g = (tid >> 4) & 3;
        const int i = tid & 15;
        int row = m0 + w * 16 + i;
        if (row >= NNODES) row = NNODES - 1;          // dup-load; stores guarded
        const short* src = A + (size_t)row * KPAD + g * 8;
        short* dst = sA + ((size_t)(w * NKSTEP) * 64 + lane) * 8;
#pragma unroll
        for (int p = 0; p < NKSTEP; ++p)
            *(bf16x8*)(dst + (size_t)p * 64 * 8) = *(const bf16x8*)(src + p * 32);
    }
    __syncthreads();

    // ---- MFMA: 4 m-frags x 2 n-tiles x 9 k-chunks x (hi,lo) ----
    f32x4 acc[2][4];
#pragma unroll
    for (int n = 0; n < 2; ++n)
#pragma unroll
        for (int f = 0; f < 4; ++f) acc[n][f] = (f32x4){0.f, 0.f, 0.f, 0.f};

#pragma unroll
    for (int f = 0; f < 4; ++f)
#pragma unroll
        for (int c = 0; c < NKSTEP; ++c) {
            bf16x8 a = *(const bf16x8*)(sA + ((size_t)(f * NKSTEP + c) * 64 + lane) * 8);
#pragma unroll
            for (int n = 0; n < 2; ++n) {
                acc[n][f] = __builtin_amdgcn_mfma_f32_16x16x32_bf16(a, bh[n][c], acc[n][f], 0, 0, 0);
                acc[n][f] = __builtin_amdgcn_mfma_f32_16x16x32_bf16(a, bl[n][c], acc[n][f], 0, 0, 0);
            }
        }

    // ---- ELU + store (C/D: col = lane&15, row = (lane>>4)*4 + reg) ----
    const int colb = w * 32 + (lane & 15);
    const int rsub = (lane >> 4) << 2;
#pragma unroll
    for (int n = 0; n < 2; ++n)
#pragma unroll
        for (int f = 0; f < 4; ++f)
#pragma unroll
            for (int r = 0; r < 4; ++r) {
                int row = m0 + f * 16 + rsub + r;
                if (row < NNODES) {
                    float v = acc[n][f][r];
                    v = v > 0.f ? v : expm1f(v);
                    out[(size_t)row * NDOUT + colb + n * 16] = v;
                }
            }
}

extern "C" void kernel_launch(void* const* d_in, const int* in_sizes, int n_in,
                              void* d_out, int out_size, void* d_ws, size_t ws_size,
                              hipStream_t stream)
{
    const float* h    = (const float*)d_in[0];   // [N,128]
    const float* et   = (const float*)d_in[1];   // [E,16]
    const float* W    = (const float*)d_in[2];   // [272,128]
    const int*   nidx = (const int*)d_in[3];     // [E]
    const int*   eidx = (const int*)d_in[4];     // [E]
    // d_in[5] = segment_ids: unused (fixed degree 16, sorted -> seg = e/16)

    short* A  = (short*)d_ws;                    // [N][288] bf16 = 57.6 MB
    short* Bh = A + (size_t)NNODES * KPAD;       // fragment-packed W hi (73.7 KB)
    short* Bl = Bh + (size_t)NKSTEP * 8 * 64 * 8;
    float* out = (float*)d_out;                  // [N,128]

    // Prep (independent)
    wt_pack_kernel<<<(NKSTEP * 8 * 64 + 255) / 256, 256, 0, stream>>>(W, Bh, Bl);
    prep_h_kernel<<<(NNODES * 16 + 255) / 256, 256, 0, stream>>>(h, A);
    // Aggregation: one wave per node, bf16 gathers
    agg_kernel<<<(NNODES * 64 + 255) / 256, 256, 0, stream>>>(A, et, nidx, eidx);
    // GEMM + ELU: register-resident B, fragment-ordered LDS A
    gemm_kernel<<<(NNODES + 63) / 64, 256, 0, stream>>>(A, Bh, Bl, out);
}

// Round 5
// 310.095 us; speedup vs baseline: 1.3072x; 1.0125x over previous
//
#include <hip/hip_runtime.h>
#include <cstdint>

#define NNODES 100000
#define NDEG 16
#define DFEAT 128      // node feature dim
#define DEDGE 16       // edge feature dim
#define KDIM  272      // 2*DFEAT + DEDGE
#define KPAD  288      // padded to 9*32 for MFMA K-steps
#define NDOUT 128
#define NKSTEP 9       // KPAD/32

typedef __attribute__((ext_vector_type(8))) short bf16x8;
typedef __attribute__((ext_vector_type(4))) short s16x4;
typedef __attribute__((ext_vector_type(4))) float f32x4;

__device__ __forceinline__ unsigned short f32_to_bf16_rn(float x) {
    union { float f; unsigned u; } v; v.f = x;
    unsigned r = v.u + 0x7FFF + ((v.u >> 16) & 1);
    return (unsigned short)(r >> 16);
}
__device__ __forceinline__ float bf16_bits_to_f32(unsigned short b) {
    union { unsigned u; float f; } v; v.u = ((unsigned)b) << 16; return v.f;
}

// ---------------------------------------------------------------------------
// Prep A: A[n][k] bf16, k<128 = hi(h[n][k]).  (k>=128 written by agg_kernel.)
// ---------------------------------------------------------------------------
__global__ __launch_bounds__(256) void prep_h_kernel(
    const float* __restrict__ h, short* __restrict__ A)
{
    int t = blockIdx.x * 256 + threadIdx.x;
    if (t >= NNODES * 16) return;
    int n  = t >> 4;
    int c8 = t & 15;
    const float4* __restrict__ h4 = (const float4*)h;
    float4 v0 = h4[(size_t)n * 32 + c8 * 2];
    float4 v1 = h4[(size_t)n * 32 + c8 * 2 + 1];
    bf16x8 o;
    o[0] = (short)f32_to_bf16_rn(v0.x); o[1] = (short)f32_to_bf16_rn(v0.y);
    o[2] = (short)f32_to_bf16_rn(v0.z); o[3] = (short)f32_to_bf16_rn(v0.w);
    o[4] = (short)f32_to_bf16_rn(v1.x); o[5] = (short)f32_to_bf16_rn(v1.y);
    o[6] = (short)f32_to_bf16_rn(v1.z); o[7] = (short)f32_to_bf16_rn(v1.w);
    *(bf16x8*)(A + (size_t)n * KPAD + c8 * 8) = o;
}

// ---------------------------------------------------------------------------
// Prep W: pack W [272][128] f32 into MFMA-fragment-ordered bf16 hi/lo.
// ---------------------------------------------------------------------------
__global__ __launch_bounds__(256) void wt_pack_kernel(
    const float* __restrict__ W, short* __restrict__ Bh, short* __restrict__ Bl)
{
    int t = blockIdx.x * 256 + threadIdx.x;
    if (t >= NKSTEP * 8 * 64) return;
    int c   = t >> 9;
    int rem = t & 511;
    int n   = rem >> 6;
    int l   = rem & 63;
    int col = n * 16 + (l & 15);
    int kb  = l >> 4;
    bf16x8 hv, lv;
#pragma unroll
    for (int j = 0; j < 8; ++j) {
        int k = c * 32 + kb * 8 + j;
        float val = (k < KDIM) ? W[(size_t)k * NDOUT + col] : 0.0f;
        unsigned short hi = f32_to_bf16_rn(val);
        unsigned short lo = f32_to_bf16_rn(val - bf16_bits_to_f32(hi));
        hv[j] = (short)hi; lv[j] = (short)lv[j];
        hv[j] = (short)hi; lv[j] = (short)lo;
    }
    *(bf16x8*)(Bh + (size_t)t * 8) = hv;
    *(bf16x8*)(Bl + (size_t)t * 8) = lv;
}

// ---------------------------------------------------------------------------
// Aggregation: one wave per node (node = n0 + wave-id; grid covers half the
// nodes per launch — split into 2 dispatches purely so the profiler's top-5
// cutoff drops below the gemm kernel).  Logic identical to R3/R4.
// ---------------------------------------------------------------------------
__global__ __launch_bounds__(256) void agg_kernel(
    short* __restrict__ A, const float* __restrict__ et,
    const int* __restrict__ nidx, const int* __restrict__ eidx, int n0)
{
    int gwave = (blockIdx.x * 256 + threadIdx.x) >> 6;
    int lane  = threadIdx.x & 63;
    const int n = n0 + gwave;
    if (n >= NNODES) return;
    const int c8 = lane & 15;
    const int g  = lane >> 4;
    const float inv = 1.0f / 16.0f;

    float acc[8];
#pragma unroll
    for (int j = 0; j < 8; ++j) acc[j] = 0.f;
#pragma unroll
    for (int t = 0; t < 4; ++t) {
        int nbr = nidx[n * NDEG + t * 4 + g];
        bf16x8 v = *(const bf16x8*)(A + (size_t)nbr * KPAD + c8 * 8);
#pragma unroll
        for (int j = 0; j < 8; ++j) acc[j] += bf16_bits_to_f32((unsigned short)v[j]);
    }
#pragma unroll
    for (int j = 0; j < 8; ++j) {
        acc[j] += __shfl_xor(acc[j], 16);
        acc[j] += __shfl_xor(acc[j], 32);
    }
    if (g == 0) {
        bf16x8 o;
#pragma unroll
        for (int j = 0; j < 8; ++j) o[j] = (short)f32_to_bf16_rn(acc[j] * inv);
        *(bf16x8*)(A + (size_t)n * KPAD + DFEAT + c8 * 8) = o;
    }

    const float4* __restrict__ et4 = (const float4*)et;
    int ke = lane >> 2, q = lane & 3;
    int e = eidx[n * NDEG + ke];
    float4 ev = et4[(size_t)e * (DEDGE / 4) + q];
#pragma unroll
    for (int m = 4; m < 64; m <<= 1) {
        ev.x += __shfl_xor(ev.x, m);
        ev.y += __shfl_xor(ev.y, m);
        ev.z += __shfl_xor(ev.z, m);
        ev.w += __shfl_xor(ev.w, m);
    }
    if (lane < 4) {
        s16x4 o;
        o[0] = (short)f32_to_bf16_rn(ev.x * inv);
        o[1] = (short)f32_to_bf16_rn(ev.y * inv);
        o[2] = (short)f32_to_bf16_rn(ev.z * inv);
        o[3] = (short)f32_to_bf16_rn(ev.w * inv);
        *(s16x4*)(A + (size_t)n * KPAD + 256 + lane * 4) = o;
    }
    if (lane == 4) *(bf16x8*)(A + (size_t)n * KPAD + 272) = (bf16x8)0;
    if (lane == 5) *(bf16x8*)(A + (size_t)n * KPAD + 280) = (bf16x8)0;
}

// ---------------------------------------------------------------------------
// GEMM + ELU: out = elu(A_bf16 @ (W_hi + W_lo)).
// Block = 64 rows x 128 cols, 4 waves.  B-frags register-resident (144 VGPR).
// A staged fragment-ordered via global_load_lds (wave-uniform LDS base +
// lane*16; per-lane GLOBAL source carries the layout) -> no VGPR round-trip,
// no ds_write, and compute ds_read_b128 is lane-linear (conflict-free).
// Epilogue ELU uses __expf (v_exp_f32) instead of libm expm1f.
// ---------------------------------------------------------------------------
__global__ __launch_bounds__(256, 2) void gemm_kernel(
    const short* __restrict__ A, const short* __restrict__ Bh,
    const short* __restrict__ Bl, float* __restrict__ out)
{
    __shared__ short sA[4 * NKSTEP * 64 * 8];   // 36 KB, fragment-ordered

    const int tid  = threadIdx.x;
    const int w    = tid >> 6;
    const int lane = tid & 63;
    const int m0   = blockIdx.x * 64;

    // ---- A staging: wave w stages its 16 rows (f = w), 9 chunks x 1KB ----
    {
        int row = m0 + w * 16 + (lane & 15);
        if (row >= NNODES) row = NNODES - 1;          // dup-load; stores guarded
        const short* src = A + (size_t)row * KPAD + (lane >> 4) * 8;
        short* dstbase = sA + (size_t)(w * NKSTEP) * 512;   // 512 shorts per chunk
#pragma unroll
        for (int j = 0; j < NKSTEP; ++j) {
            __builtin_amdgcn_global_load_lds(
                (const __attribute__((address_space(1))) void*)(src + j * 32),
                (__attribute__((address_space(3))) void*)(dstbase + j * 512),
                16, 0, 0);
        }
    }

    // ---- B preload: n-tiles {2w, 2w+1}, all k-chunks (coalesced, L2-hot) ----
    bf16x8 bh[2][NKSTEP], bl[2][NKSTEP];
#pragma unroll
    for (int n = 0; n < 2; ++n)
#pragma unroll
        for (int c = 0; c < NKSTEP; ++c) {
            size_t off = ((size_t)(c * 8 + (w * 2 + n)) * 64 + lane) * 8;
            bh[n][c] = *(const bf16x8*)(Bh + off);
            bl[n][c] = *(const bf16x8*)(Bl + off);
        }

    __syncthreads();   // drains vmcnt (global_load_lds) before any ds_read

    // ---- MFMA: 4 m-frags x 9 k-chunks x 2 n-tiles x (hi,lo) ----
    f32x4 acc[2][4];
#pragma unroll
    for (int n = 0; n < 2; ++n)
#pragma unroll
        for (int f = 0; f < 4; ++f) acc[n][f] = (f32x4){0.f, 0.f, 0.f, 0.f};

#pragma unroll
    for (int f = 0; f < 4; ++f)
#pragma unroll
        for (int c = 0; c < NKSTEP; ++c) {
            bf16x8 a = *(const bf16x8*)(sA + ((size_t)(f * NKSTEP + c) * 64 + lane) * 8);
#pragma unroll
            for (int n = 0; n < 2; ++n) {
                acc[n][f] = __builtin_amdgcn_mfma_f32_16x16x32_bf16(a, bh[n][c], acc[n][f], 0, 0, 0);
                acc[n][f] = __builtin_amdgcn_mfma_f32_16x16x32_bf16(a, bl[n][c], acc[n][f], 0, 0, 0);
            }
        }

    // ---- ELU + store (C/D: col = lane&15, row = (lane>>4)*4 + reg) ----
    const int colb = w * 32 + (lane & 15);
    const int rsub = (lane >> 4) << 2;
#pragma unroll
    for (int n = 0; n < 2; ++n)
#pragma unroll
        for (int f = 0; f < 4; ++f)
#pragma unroll
            for (int r = 0; r < 4; ++r) {
                int row = m0 + f * 16 + rsub + r;
                if (row < NNODES) {
                    float v = acc[n][f][r];
                    v = v > 0.f ? v : (__expf(v) - 1.0f);
                    out[(size_t)row * NDOUT + colb + n * 16] = v;
                }
            }
}

extern "C" void kernel_launch(void* const* d_in, const int* in_sizes, int n_in,
                              void* d_out, int out_size, void* d_ws, size_t ws_size,
                              hipStream_t stream)
{
    const float* h    = (const float*)d_in[0];   // [N,128]
    const float* et   = (const float*)d_in[1];   // [E,16]
    const float* W    = (const float*)d_in[2];   // [272,128]
    const int*   nidx = (const int*)d_in[3];     // [E]
    const int*   eidx = (const int*)d_in[4];     // [E]
    // d_in[5] = segment_ids: unused (fixed degree 16, sorted -> seg = e/16)

    short* A  = (short*)d_ws;                    // [N][288] bf16 = 57.6 MB
    short* Bh = A + (size_t)NNODES * KPAD;       // fragment-packed W hi (73.7 KB)
    short* Bl = Bh + (size_t)NKSTEP * 8 * 64 * 8;
    float* out = (float*)d_out;                  // [N,128]

    // Prep (independent)
    wt_pack_kernel<<<(NKSTEP * 8 * 64 + 255) / 256, 256, 0, stream>>>(W, Bh, Bl);
    prep_h_kernel<<<(NNODES * 16 + 255) / 256, 256, 0, stream>>>(h, A);
    // Aggregation: split into 2 half-grids (diagnostic: lowers top-5 cutoff)
    {
        const int HALF = 50000;                          // nodes per dispatch
        int blocks = (HALF * 64) / 256;                  // 12500
        agg_kernel<<<blocks, 256, 0, stream>>>(A, et, nidx, eidx, 0);
        agg_kernel<<<blocks, 256, 0, stream>>>(A, et, nidx, eidx, HALF);
    }
    // GEMM + ELU: register-resident B, global_load_lds fragment-ordered A
    gemm_kernel<<<(NNODES + 63) / 64, 256, 0, stream>>>(A, Bh, Bl, out);
}